// Round 4
// baseline (78.949 us; speedup 1.0000x reference)
//
#include <hip/hip_runtime.h>
#include <cstdint>

#define BATCH 8
#define CIN 64
#define COUT 128
#define HH 32
#define WW 32

typedef int v4i __attribute__((ext_vector_type(4)));
typedef float v4f __attribute__((ext_vector_type(4)));

// ---------------- workspace layout ----------------
// f32[16..143]  : x absmax partials (128 blocks)
// f32[160..183] : w absmax partials (24 blocks)
#define WS_PX 16
#define WS_PW 160

// LDS tile: 3 rows x 34 px x 72 B/pixel (18 dwords: 16 data + 2 pad)
#define TPITCH 18

__device__ __forceinline__ unsigned quantb(float v, float scale) {
    float q = rintf(v * scale);
    q = fminf(fmaxf(q, -128.0f), 127.0f);
    return ((unsigned)(int)q) & 255u;
}

// =====================================================================
// kernel 1: absmax partials only — uniformly tiny blocks.
// blocks 0..127 : x partials (4 float4/thread over 2 MB)
// blocks 128..151: w partials (3 float4/thread over 288 KB)
// =====================================================================
__global__ __launch_bounds__(256) void partials(const float* __restrict__ x,
                                                const float* __restrict__ w,
                                                float* __restrict__ ws_f32) {
    int blk = blockIdx.x;
    int t = threadIdx.x;
    int lane = t & 63;
    int wave = t >> 6;
    __shared__ float sm[4];

    float m = 0.0f;
    if (blk < 128) {
        const float4* p = (const float4*)x;
        int base = blk * 1024 + t;
        #pragma unroll
        for (int k = 0; k < 4; ++k) {
            float4 v = p[base + k * 256];
            m = fmaxf(m, fmaxf(fmaxf(fabsf(v.x), fabsf(v.y)), fmaxf(fabsf(v.z), fabsf(v.w))));
        }
    } else {
        const float4* p = (const float4*)w;
        int base = (blk - 128) * 768 + t;
        #pragma unroll
        for (int k = 0; k < 3; ++k) {
            float4 v = p[base + k * 256];
            m = fmaxf(m, fmaxf(fmaxf(fabsf(v.x), fabsf(v.y)), fmaxf(fabsf(v.z), fabsf(v.w))));
        }
    }
    #pragma unroll
    for (int off = 32; off > 0; off >>= 1)
        m = fmaxf(m, __shfl_xor(m, off, 64));
    if (lane == 0) sm[wave] = m;
    __syncthreads();
    if (t == 0) {
        float r = fmaxf(fmaxf(sm[0], sm[1]), fmaxf(sm[2], sm[3]));
        if (blk < 128) ws_f32[WS_PX + blk] = r;
        else           ws_f32[WS_PW + (blk - 128)] = r;
    }
}

// =====================================================================
// kernel 2: everything else, fused. 512 blocks (b, oh, nb), 2/CU.
// Per block: Tf/Tw from partials (shuffle-only); quantize own 64-cout
// B-slice from w into 36 KB LDS (contiguous 9-float4-per-job gather);
// quantize own 3-row x halo into NHWC LDS tile (v_perm 4x4 transpose);
// ONE barrier; 9-tap MFMA with A and B both from LDS; scaled epilogue.
// =====================================================================
__global__ __launch_bounds__(256, 2) void conv_fused(const float* __restrict__ x,
                                                     const float* __restrict__ w,
                                                     const float* __restrict__ bias,
                                                     const float* __restrict__ Tf_in,
                                                     const float* __restrict__ Tw_in,
                                                     const float* __restrict__ ws_f32,
                                                     float* __restrict__ out) {
    int blk = blockIdx.x;
    int t = threadIdx.x;
    int lane = t & 63;
    int wave = t >> 6;
    int nb = blk & 1;
    int mb = blk >> 1;
    int b = mb >> 5;
    int oh = mb & 31;

    __shared__ unsigned tile[3 * 34 * TPITCH];     // 7344 B, A halo tile
    __shared__ unsigned bfrag[9 * 4 * 64 * 4];     // 36864 B, [tap][gl][ln][4dw]

    // ---- Tf / Tw from partials (per-wave redundant; no barrier) ----
    float p0 = ws_f32[WS_PX + lane];
    float p1 = ws_f32[WS_PX + 64 + lane];
    float pw = ws_f32[WS_PW + (lane < 24 ? lane : 0)];
    float mx = fmaxf(p0, p1);
    #pragma unroll
    for (int off = 32; off > 0; off >>= 1) {
        mx = fmaxf(mx, __shfl_xor(mx, off, 64));
        pw = fmaxf(pw, __shfl_xor(pw, off, 64));
    }
    float Tf = 0.95f * Tf_in[0] + 0.05f * mx;
    float Tw = 0.95f * Tw_in[0] + 0.05f * pw;
    float scf = 127.0f / Tf;
    float scw = 127.0f / Tw;

    // ---- zero-fill tile borders (96 dw); OOB row for oh 0/31 ----
    if (t < 96) {
        int rr = t >> 5;
        int rest = t & 31;
        int side = rest >> 4;
        int kk = rest & 15;
        tile[(rr * 34 + side * 33) * TPITCH + kk] = 0u;
    }
    if (oh == 0 || oh == 31) {
        int rbad = (oh == 0) ? 0 : 2;
        #pragma unroll
        for (int k = 0; k < 3; ++k) {
            int i = t + k * 256;
            if (i < 544) {
                int px = i >> 4, kk = i & 15;
                tile[(rbad * 34 + px) * TPITCH + kk] = 0u;
            }
        }
    }

    // ---- B-quant: w slice [nb*64, nb*64+64) -> bfrag LDS ----
    // 1024 jobs = 4 k-iters; job (gl=k, ln=t>>2, j0g=t&3).
    // Each job: 9 aligned float4 = 36 floats = 4 ci x 9 taps, contiguous.
    {
        int co0 = nb * 64;
        int ln = t >> 2;
        int j0g = t & 3;
        const float4* w4 = (const float4*)w;
        #pragma unroll
        for (int gl = 0; gl < 4; ++gl) {
            int co = co0 + gl * 16 + (ln & 15);
            int ci0 = (ln >> 4) * 16 + j0g * 4;
            int F0 = co * 576 + ci0 * 9;          // float index, %4 == 0
            float4 r0 = w4[(F0 >> 2) + 0];
            float4 r1 = w4[(F0 >> 2) + 1];
            float4 r2 = w4[(F0 >> 2) + 2];
            float4 r3 = w4[(F0 >> 2) + 3];
            float4 r4 = w4[(F0 >> 2) + 4];
            float4 r5 = w4[(F0 >> 2) + 5];
            float4 r6 = w4[(F0 >> 2) + 6];
            float4 r7 = w4[(F0 >> 2) + 7];
            float4 r8 = w4[(F0 >> 2) + 8];
            float fl[36];
            *(float4*)&fl[0]  = r0; *(float4*)&fl[4]  = r1; *(float4*)&fl[8]  = r2;
            *(float4*)&fl[12] = r3; *(float4*)&fl[16] = r4; *(float4*)&fl[20] = r5;
            *(float4*)&fl[24] = r6; *(float4*)&fl[28] = r7; *(float4*)&fl[32] = r8;
            #pragma unroll
            for (int tap = 0; tap < 9; ++tap) {
                // local float index for (ci-local c, tap) = c*9 + tap  (static)
                unsigned pk = quantb(fl[tap], scw)
                            | (quantb(fl[9 + tap], scw) << 8)
                            | (quantb(fl[18 + tap], scw) << 16)
                            | (quantb(fl[27 + tap], scw) << 24);
                bfrag[tap * 1024 + gl * 256 + t] = pk;
            }
        }
    }

    // ---- x-stage: quantize + v_perm 4x4 transpose -> NHWC tile ----
    // 384 jobs: j -> (r = j>>7, wq = (j&127)>>4, g4 = j&15)
    const float4* x4 = (const float4*)x;
    #pragma unroll
    for (int k = 0; k < 2; ++k) {
        int j = t + k * 256;
        if (j < 384) {
            int r = j >> 7;
            int rem = j & 127;
            int wq = rem >> 4;
            int g4 = rem & 15;
            int ih = oh - 1 + r;
            if (ih >= 0 && ih < HH) {
                int xb = (b * CIN + g4 * 4) * 256 + ih * 8 + wq;
                float4 v0 = x4[xb];
                float4 v1 = x4[xb + 256];
                float4 v2 = x4[xb + 512];
                float4 v3 = x4[xb + 768];
                unsigned P0 = quantb(v0.x, scf) | (quantb(v0.y, scf) << 8) |
                              (quantb(v0.z, scf) << 16) | (quantb(v0.w, scf) << 24);
                unsigned P1 = quantb(v1.x, scf) | (quantb(v1.y, scf) << 8) |
                              (quantb(v1.z, scf) << 16) | (quantb(v1.w, scf) << 24);
                unsigned P2 = quantb(v2.x, scf) | (quantb(v2.y, scf) << 8) |
                              (quantb(v2.z, scf) << 16) | (quantb(v2.w, scf) << 24);
                unsigned P3 = quantb(v3.x, scf) | (quantb(v3.y, scf) << 8) |
                              (quantb(v3.z, scf) << 16) | (quantb(v3.w, scf) << 24);
                unsigned Q0 = __builtin_amdgcn_perm(P1, P0, 0x05040100u);
                unsigned Q1 = __builtin_amdgcn_perm(P1, P0, 0x07060302u);
                unsigned Q2 = __builtin_amdgcn_perm(P3, P2, 0x05040100u);
                unsigned Q3 = __builtin_amdgcn_perm(P3, P2, 0x07060302u);
                unsigned D0 = __builtin_amdgcn_perm(Q2, Q0, 0x06040200u);
                unsigned D1 = __builtin_amdgcn_perm(Q2, Q0, 0x07050301u);
                unsigned D2 = __builtin_amdgcn_perm(Q3, Q1, 0x06040200u);
                unsigned D3 = __builtin_amdgcn_perm(Q3, Q1, 0x07050301u);
                int base = (r * 34 + wq * 4 + 1) * TPITCH + g4;
                tile[base]              = D0;
                tile[base + TPITCH]     = D1;
                tile[base + 2 * TPITCH] = D2;
                tile[base + 3 * TPITCH] = D3;
            }
        }
    }
    __syncthreads();

    // ---- conv: 9-tap MFMA, A and B both from LDS ----
    int mt = wave & 1;            // pixel half (16 pixels)
    int nh2 = wave >> 1;          // cout sub-half -> gl = nh2*2 + nt
    int row = lane & 15;
    int quad = lane >> 4;
    int px0 = mt * 16 + row;

    v4i acc[2];
    acc[0] = (v4i){0, 0, 0, 0};
    acc[1] = (v4i){0, 0, 0, 0};

    const int2* tl2 = (const int2*)tile;
    const v4i* bf4 = (const v4i*)bfrag;

    #pragma unroll
    for (int tp = 0; tp < 9; ++tp) {
        const int kh = tp / 3, kw = tp % 3;
        int d = ((kh * 34) + px0 + kw) * TPITCH + quad * 4;   // even -> 8B aligned
        int2 lo = tl2[(d >> 1)];
        int2 hi = tl2[(d >> 1) + 1];
        v4i afrag = (v4i){lo.x, lo.y, hi.x, hi.y};
        #pragma unroll
        for (int nt = 0; nt < 2; ++nt) {
            int gl = nh2 * 2 + nt;
            v4i bv = bf4[(tp * 4 + gl) * 64 + lane];
            acc[nt] = __builtin_amdgcn_mfma_i32_16x16x64_i8(afrag, bv, acc[nt], 0, 0, 0);
        }
    }

    float s = (Tf / 127.0f) * (Tw / 127.0f);
    int ow0 = mt * 16 + quad * 4;
    #pragma unroll
    for (int nt = 0; nt < 2; ++nt) {
        int gl = nh2 * 2 + nt;
        int co = nb * 64 + gl * 16 + row;
        float bb = bias[co];
        v4f o;
        o.x = (float)acc[nt][0] * s + bb;
        o.y = (float)acc[nt][1] * s + bb;
        o.z = (float)acc[nt][2] * s + bb;
        o.w = (float)acc[nt][3] * s + bb;
        __builtin_nontemporal_store(o, (v4f*)(out + (((b * COUT + co) * HH + oh) * WW) + ow0));
    }
}

extern "C" void kernel_launch(void* const* d_in, const int* in_sizes, int n_in,
                              void* d_out, int out_size, void* d_ws, size_t ws_size,
                              hipStream_t stream) {
    const float* x         = (const float*)d_in[0];
    const float* weight    = (const float*)d_in[1];
    const float* bias      = (const float*)d_in[2];
    const float* T_feature = (const float*)d_in[5];
    const float* T_weight  = (const float*)d_in[6];

    float* ws_f32 = (float*)d_ws;

    partials<<<152, 256, 0, stream>>>(x, weight, ws_f32);
    conv_fused<<<512, 256, 0, stream>>>(x, weight, bias, T_feature, T_weight,
                                        ws_f32, (float*)d_out);
}